// Round 1
// baseline (204.407 us; speedup 1.0000x reference)
//
#include <hip/hip_runtime.h>

// ---------------------------------------------------------------------------
// PriceGeometryEncoder on MI355X.
// Pipeline: prep -> embed(f32) -> 6x MLP GEMM (bf16 MFMA) -> QKV GEMM ->
//           V-transpose -> flash attention (32x32 swapped-QK^T, mean-pooled
//           via atomics) -> tiny f32 head.
// Key trick: out = (mean_t(o) @ Wo + bo) @ Wout + bout  (mean commutes with
// the linear layers), so attention only emits column sums of O.
// ---------------------------------------------------------------------------

#define B_   16
#define T_   2048
#define E_   128
#define HH   4
#define DH   32
#define BH_  (B_*HH)

typedef __attribute__((ext_vector_type(4)))  float f32x4;
typedef __attribute__((ext_vector_type(16))) float f32x16;
typedef __attribute__((ext_vector_type(4)))  short short4v;
typedef __attribute__((ext_vector_type(8)))  short short8v;

static __device__ __forceinline__ unsigned short f2b(float f) {
    unsigned int u = __builtin_bit_cast(unsigned int, f);
    u += 0x7fffu + ((u >> 16) & 1u);       // round-to-nearest-even
    return (unsigned short)(u >> 16);
}

static __device__ __forceinline__ unsigned int cvtpk_bf16(float a, float b) {
    unsigned int r;
    asm volatile("v_cvt_pk_bf16_f32 %0, %1, %2" : "=v"(r) : "v"(a), "v"(b));
    return r;
}

// ---------------------------------------------------------------------------
// K0: weight transposes (f32 -> bf16 [N][K]) + zero the pooled accumulator.
// ---------------------------------------------------------------------------
__global__ __launch_bounds__(256) void prep_kernel(
    const float* Wc1, const float* Wc2, const float* Wv1, const float* Wv2,
    const float* Ws1, const float* Ws2, const float* Wqkv,
    unsigned short* wc1t, unsigned short* wc2t, unsigned short* wv1t,
    unsigned short* wv2t, unsigned short* ws1t, unsigned short* ws2t,
    unsigned short* wqkvt, float* pooled)
{
    int idx = blockIdx.x * 256 + threadIdx.x;
    if (idx < 8192)  { int n = idx >> 6, kk = idx & 63;  wc1t[idx] = f2b(Wc1[kk*128 + n]); return; }
    idx -= 8192;
    if (idx < 4096)  { int n = idx >> 7, kk = idx & 127; wc2t[idx] = f2b(Wc2[kk*32  + n]); return; }
    idx -= 4096;
    if (idx < 4096)  { int n = idx >> 6, kk = idx & 63;  wv1t[idx] = f2b(Wv1[kk*64  + n]); return; }
    idx -= 4096;
    if (idx < 1024)  { int n = idx >> 6, kk = idx & 63;  wv2t[idx] = f2b(Wv2[kk*16  + n]); return; }
    idx -= 1024;
    if (idx < 4096)  { int n = idx >> 6, kk = idx & 63;  ws1t[idx] = f2b(Ws1[kk*64  + n]); return; }
    idx -= 4096;
    if (idx < 1024)  { int n = idx >> 6, kk = idx & 63;  ws2t[idx] = f2b(Ws2[kk*16  + n]); return; }
    idx -= 1024;
    if (idx < 49152) { int n = idx >> 7, kk = idx & 127; wqkvt[idx] = f2b(Wqkv[kk*384 + n]); return; }
    idx -= 49152;
    if (idx < 2048)  pooled[idx] = 0.f;
}

// ---------------------------------------------------------------------------
// K1: e = ohlc @ Wp + bp  (K=4, pure f32 VALU), written to feats[:, 0:64].
// ---------------------------------------------------------------------------
__global__ __launch_bounds__(256) void embed_kernel(
    const float* __restrict__ ohlc, const float* __restrict__ Wp,
    const float* __restrict__ bp, unsigned short* __restrict__ feats)
{
    __shared__ float wp[256];
    __shared__ float bps[64];
    int tid = threadIdx.x;
    wp[tid] = Wp[tid];
    if (tid < 64) bps[tid] = bp[tid];
    __syncthreads();

    int t = blockIdx.x * 256 + tid;
    float4 ov = ((const float4*)ohlc)[t];
    unsigned short* dst = feats + (size_t)t * 128;
#pragma unroll
    for (int g = 0; g < 8; ++g) {
        union { unsigned short us[8]; short8v v; } pk;
#pragma unroll
        for (int jj = 0; jj < 8; ++jj) {
            int j = g * 8 + jj;
            float e = bps[j] + ov.x * wp[j] + ov.y * wp[64 + j]
                             + ov.z * wp[128 + j] + ov.w * wp[192 + j];
            pk.us[jj] = f2b(e);
        }
        *(short8v*)(dst + g * 8) = pk.v;
    }
}

// ---------------------------------------------------------------------------
// Generic MLP GEMM: Out[m, 0:N] = act(A[m, 0:K] @ B + bias), bf16 in/out,
// f32 accum. BT is [N][K] (pre-transposed). BM=128, 4 waves x 32 rows.
// LDS rows XOR-swizzled in 16B slots -> <=2-way bank conflicts on ds_read_b128.
// ---------------------------------------------------------------------------
template<int N, int K, bool RELU>
__global__ __launch_bounds__(256) void mlp_gemm(
    const unsigned short* __restrict__ A, int lda,
    const unsigned short* __restrict__ BT, const float* __restrict__ bias,
    unsigned short* __restrict__ Out, int ldo)
{
    constexpr int ROWB = K * 2;       // LDS row bytes
    constexpr int SL   = ROWB / 16;   // 16B slots per row
    constexpr int CPR  = K / 8;       // 16B chunks per row
    constexpr int NT   = N / 16;
    __shared__ char As[128 * ROWB];
    __shared__ char Bs[N * ROWB];

    int tid = threadIdx.x;
    int m0 = blockIdx.x * 128;

    for (int c = tid; c < 128 * CPR; c += 256) {
        int m = c / CPR, s = c % CPR;
        short8v v = *(const short8v*)(A + (size_t)(m0 + m) * lda + s * 8);
        *(short8v*)(As + m * ROWB + ((s ^ (m & (SL - 1))) * 16)) = v;
    }
    for (int c = tid; c < N * CPR; c += 256) {
        int n = c / CPR, s = c % CPR;
        short8v v = *(const short8v*)(BT + (size_t)n * K + s * 8);
        *(short8v*)(Bs + n * ROWB + ((s ^ (n & (SL - 1))) * 16)) = v;
    }
    __syncthreads();

    int lane = tid & 63, w = tid >> 6;
    int l15 = lane & 15, hi4 = lane >> 4;

    f32x4 acc[2][NT];
#pragma unroll
    for (int mt = 0; mt < 2; ++mt)
#pragma unroll
        for (int nt = 0; nt < NT; ++nt)
#pragma unroll
            for (int r = 0; r < 4; ++r) acc[mt][nt][r] = 0.f;

#pragma unroll
    for (int ks = 0; ks < K / 32; ++ks) {
        int slot = ks * 4 + hi4;
        short8v af[2];
#pragma unroll
        for (int mt = 0; mt < 2; ++mt) {
            int m = w * 32 + mt * 16 + l15;
            af[mt] = *(const short8v*)(As + m * ROWB + ((slot ^ (m & (SL - 1))) * 16));
        }
#pragma unroll
        for (int nt = 0; nt < NT; ++nt) {
            int n = nt * 16 + l15;
            short8v bf = *(const short8v*)(Bs + n * ROWB + ((slot ^ (n & (SL - 1))) * 16));
            acc[0][nt] = __builtin_amdgcn_mfma_f32_16x16x32_bf16(af[0], bf, acc[0][nt], 0, 0, 0);
            acc[1][nt] = __builtin_amdgcn_mfma_f32_16x16x32_bf16(af[1], bf, acc[1][nt], 0, 0, 0);
        }
    }

#pragma unroll
    for (int mt = 0; mt < 2; ++mt)
#pragma unroll
        for (int nt = 0; nt < NT; ++nt) {
            int n = nt * 16 + l15;
            float bv = bias[n];
#pragma unroll
            for (int r = 0; r < 4; ++r) {
                int m = m0 + w * 32 + mt * 16 + hi4 * 4 + r;
                float v = acc[mt][nt][r] + bv;
                if (RELU) v = fmaxf(v, 0.f);
                Out[(size_t)m * ldo + n] = f2b(v);
            }
        }
}

// ---------------------------------------------------------------------------
// K3: QKV GEMM (M=32768, K=128), blockIdx.y selects q/k/v third.
// q gets *QSCALE (log2e/sqrt(32)); outputs land in [b*H+h][t][dh] layout.
// ---------------------------------------------------------------------------
__global__ __launch_bounds__(256) void qkv_gemm(
    const unsigned short* __restrict__ feats,
    const unsigned short* __restrict__ wqkvt, const float* __restrict__ bqkv,
    unsigned short* __restrict__ qg, unsigned short* __restrict__ kg,
    unsigned short* __restrict__ vg)
{
    constexpr int ROWB = 256, SL = 16, CPR = 16;
    __shared__ char As[128 * ROWB];
    __shared__ char Bs[128 * ROWB];

    int tid = threadIdx.x;
    int m0 = blockIdx.x * 128;
    int sel = blockIdx.y;
    const unsigned short* BT = wqkvt + (size_t)sel * 128 * 128;

    for (int c = tid; c < 128 * CPR; c += 256) {
        int m = c / CPR, s = c % CPR;
        short8v v = *(const short8v*)(feats + (size_t)(m0 + m) * 128 + s * 8);
        *(short8v*)(As + m * ROWB + ((s ^ (m & (SL - 1))) * 16)) = v;
    }
    for (int c = tid; c < 128 * CPR; c += 256) {
        int n = c / CPR, s = c % CPR;
        short8v v = *(const short8v*)(BT + (size_t)n * 128 + s * 8);
        *(short8v*)(Bs + n * ROWB + ((s ^ (n & (SL - 1))) * 16)) = v;
    }
    __syncthreads();

    int lane = tid & 63, w = tid >> 6;
    int l15 = lane & 15, hi4 = lane >> 4;

    f32x4 acc[2][8];
#pragma unroll
    for (int mt = 0; mt < 2; ++mt)
#pragma unroll
        for (int nt = 0; nt < 8; ++nt)
#pragma unroll
            for (int r = 0; r < 4; ++r) acc[mt][nt][r] = 0.f;

#pragma unroll
    for (int ks = 0; ks < 4; ++ks) {
        int slot = ks * 4 + hi4;
        short8v af[2];
#pragma unroll
        for (int mt = 0; mt < 2; ++mt) {
            int m = w * 32 + mt * 16 + l15;
            af[mt] = *(const short8v*)(As + m * ROWB + ((slot ^ (m & 15)) * 16));
        }
#pragma unroll
        for (int nt = 0; nt < 8; ++nt) {
            int n = nt * 16 + l15;
            short8v bf = *(const short8v*)(Bs + n * ROWB + ((slot ^ (n & 15)) * 16));
            acc[0][nt] = __builtin_amdgcn_mfma_f32_16x16x32_bf16(af[0], bf, acc[0][nt], 0, 0, 0);
            acc[1][nt] = __builtin_amdgcn_mfma_f32_16x16x32_bf16(af[1], bf, acc[1][nt], 0, 0, 0);
        }
    }

    const float QSCALE = 1.4426950408889634f * 0.17677669529663687f; // log2e/sqrt(32)
#pragma unroll
    for (int mt = 0; mt < 2; ++mt)
#pragma unroll
        for (int nt = 0; nt < 8; ++nt) {
            int n = nt * 16 + l15;
            float bv = bqkv[sel * 128 + n];
#pragma unroll
            for (int r = 0; r < 4; ++r) {
                int t = m0 + w * 32 + mt * 16 + hi4 * 4 + r;
                float v = acc[mt][nt][r] + bv;
                int b = t >> 11, tp = t & 2047;
                int h = n >> 5, dh = n & 31;
                size_t o = ((size_t)((b * 4 + h) * 2048 + tp)) * 32 + dh;
                if (sel == 0)      qg[o] = f2b(v * QSCALE);
                else if (sel == 1) kg[o] = f2b(v);
                else               vg[o] = f2b(v);
            }
        }
}

// ---------------------------------------------------------------------------
// K3b: V [bh][t][32] -> V^T [bh][32][2048] (LDS tile transpose, 64-token tiles)
// ---------------------------------------------------------------------------
__global__ __launch_bounds__(256) void vtrans_kernel(
    const unsigned short* __restrict__ vin, unsigned short* __restrict__ vout)
{
    __shared__ unsigned short tile[64 * 36];   // 72B stride: 2-way write, b64-safe
    int tid = threadIdx.x, bid = blockIdx.x;
    int bh = bid >> 5, t0 = (bid & 31) * 64;

    int tok = tid >> 2, seg = tid & 3;
    short8v v = *(const short8v*)(vin + ((size_t)(bh * 2048) + t0 + tok) * 32 + seg * 8);
    union { short8v v; short4v h[2]; } u; u.v = v;
    *(short4v*)(tile + tok * 36 + seg * 8)     = u.h[0];
    *(short4v*)(tile + tok * 36 + seg * 8 + 4) = u.h[1];
    __syncthreads();

    int dh = tid >> 3, sg = tid & 7;
    union { unsigned short us[8]; short8v v; } o;
#pragma unroll
    for (int j = 0; j < 8; ++j) o.us[j] = tile[(sg * 8 + j) * 36 + dh];
    *(short8v*)(vout + ((size_t)(bh * 32) + dh) * 2048 + t0 + sg * 8) = o.v;
}

// ---------------------------------------------------------------------------
// K4: flash attention, swapped-QK^T 32x32 structure, dh=32.
// Per block: one (b,h), 128 q rows (4 waves x 32). KV tiles of 64.
// S^T = mfma(K, Q^T): lane owns q = lane&31; P stays lane-local; PV computes
// O^T = mfma(V^T, P^T) so the online-softmax rescale is per-lane-uniform.
// Output: column sums of O/lsum atomically added to pooled[b][h*32+dh].
// ---------------------------------------------------------------------------
__global__ __launch_bounds__(256) void attn_kernel(
    const unsigned short* __restrict__ qg, const unsigned short* __restrict__ kg,
    const unsigned short* __restrict__ vTg, float* __restrict__ pooled)
{
    __shared__ char Ks[64 * 72];     // [64 keys][32 kd], 72B stride (2-way b64 reads)
    __shared__ char Vs[32 * 128];    // [32 dh][64 keys], XOR-swizzled 16B slots

    int tid = threadIdx.x, bid = blockIdx.x;
    int bh = bid >> 4, qb = bid & 15;
    int b = bh >> 2, h = bh & 3;
    int lane = tid & 63, w = tid >> 6;
    int l31 = lane & 31, hi = lane >> 5;
    int q0 = qb * 128 + w * 32;

    // Q^T fragments (B operand), q pre-scaled by log2e/sqrt(32) in qkv_gemm
    const unsigned short* qrow = qg + ((size_t)(bh * 2048 + q0 + l31)) * 32;
    short8v Qf0 = *(const short8v*)(qrow + hi * 8);        // kd 0..15
    short8v Qf1 = *(const short8v*)(qrow + 16 + hi * 8);   // kd 16..31

    f32x16 accO;
#pragma unroll
    for (int r = 0; r < 16; ++r) accO[r] = 0.f;
    float m_ = -1e30f, lsum = 0.f;

    int skey = tid >> 2, sseg = tid & 3;   // K staging
    int vdh = tid >> 3, vseg = tid & 7;    // V^T staging
    const unsigned short* kbase = kg + (size_t)bh * 2048 * 32;
    const unsigned short* vbase = vTg + (size_t)bh * 32 * 2048;

    for (int kt = 0; kt < 32; ++kt) {
        int k0 = kt * 64;
        {
            short8v kv = *(const short8v*)(kbase + (size_t)(k0 + skey) * 32 + sseg * 8);
            union { short8v v; short4v h[2]; } ku; ku.v = kv;
            *(short4v*)(Ks + skey * 72 + sseg * 16)     = ku.h[0];
            *(short4v*)(Ks + skey * 72 + sseg * 16 + 8) = ku.h[1];
            short8v vv = *(const short8v*)(vbase + (size_t)vdh * 2048 + k0 + vseg * 8);
            *(short8v*)(Vs + vdh * 128 + ((vseg * 16) ^ ((vdh & 7) << 4))) = vv;
        }
        __syncthreads();

#pragma unroll
        for (int sub = 0; sub < 2; ++sub) {
            const char* arow = Ks + (sub * 32 + l31) * 72 + hi * 16;
            union { short4v h[2]; short8v v; } a0, a1;
            a0.h[0] = *(const short4v*)(arow);
            a0.h[1] = *(const short4v*)(arow + 8);
            a1.h[0] = *(const short4v*)(arow + 32);
            a1.h[1] = *(const short4v*)(arow + 40);

            f32x16 s;
#pragma unroll
            for (int r = 0; r < 16; ++r) s[r] = 0.f;
            s = __builtin_amdgcn_mfma_f32_32x32x16_bf16(a0.v, Qf0, s, 0, 0, 0);
            s = __builtin_amdgcn_mfma_f32_32x32x16_bf16(a1.v, Qf1, s, 0, 0, 0);

            // online softmax (log2 domain); lane l and l+32 share q, split keys
            float mx = s[0];
#pragma unroll
            for (int r = 1; r < 16; ++r) mx = fmaxf(mx, s[r]);
            mx = fmaxf(mx, __shfl_xor(mx, 32));
            float nm = fmaxf(m_, mx);
            float al = __builtin_amdgcn_exp2f(m_ - nm);
            float p[16];
            float ps = 0.f;
#pragma unroll
            for (int r = 0; r < 16; ++r) {
                float pv = __builtin_amdgcn_exp2f(s[r] - nm);
                p[r] = pv; ps += pv;
            }
            ps += __shfl_xor(ps, 32);
            lsum = lsum * al + ps;
#pragma unroll
            for (int r = 0; r < 16; ++r) accO[r] *= al;
            m_ = nm;

            // P (f32, lane-local rows) -> bf16 B-fragments via cvt_pk + permlane32_swap
#pragma unroll
            for (int c2 = 0; c2 < 2; ++c2) {
                unsigned int wa = cvtpk_bf16(p[c2 * 8 + 0], p[c2 * 8 + 1]);
                unsigned int wb = cvtpk_bf16(p[c2 * 8 + 2], p[c2 * 8 + 3]);
                unsigned int wc = cvtpk_bf16(p[c2 * 8 + 4], p[c2 * 8 + 5]);
                unsigned int wd = cvtpk_bf16(p[c2 * 8 + 6], p[c2 * 8 + 7]);
                asm volatile("v_permlane32_swap_b32 %0, %1" : "+v"(wa), "+v"(wc));
                asm volatile("v_permlane32_swap_b32 %0, %1" : "+v"(wb), "+v"(wd));
                union { unsigned int u[4]; short8v v; } pf;
                pf.u[0] = wa; pf.u[1] = wb; pf.u[2] = wc; pf.u[3] = wd;

                short8v vf = *(const short8v*)(Vs + l31 * 128 +
                              (((sub * 64 + c2 * 32 + hi * 16)) ^ ((l31 & 7) << 4)));
                accO = __builtin_amdgcn_mfma_f32_32x32x16_bf16(vf, pf.v, accO, 0, 0, 0);
            }
        }
        __syncthreads();
    }

    // normalize, reduce over this wave's 32 q rows, atomically add to pooled
    float inv = 1.0f / lsum;
#pragma unroll
    for (int r = 0; r < 16; ++r) {
        float v = accO[r] * inv;
        v += __shfl_xor(v, 1); v += __shfl_xor(v, 2); v += __shfl_xor(v, 4);
        v += __shfl_xor(v, 8); v += __shfl_xor(v, 16);
        if (l31 == 0) {
            int dh = (r & 3) + 8 * (r >> 2) + 4 * hi;
            atomicAdd(pooled + b * 128 + h * 32 + dh, v);
        }
    }
}

// ---------------------------------------------------------------------------
// K5: out[b] = (pooled[b]/2048 @ Wo + bo) @ Wout + bout   (f32, tiny)
// ---------------------------------------------------------------------------
__global__ __launch_bounds__(256) void head_kernel(
    const float* __restrict__ pooled, const float* __restrict__ Wo,
    const float* __restrict__ bo, const float* __restrict__ Wout,
    const float* __restrict__ bout, float* __restrict__ out)
{
    int bq = blockIdx.x, tid = threadIdx.x;
    __shared__ float pl[128], mid[128];
    if (tid < 128) pl[tid] = pooled[bq * 128 + tid] * (1.f / 2048.f);
    __syncthreads();
    if (tid < 128) {
        float s = bo[tid];
#pragma unroll 4
        for (int c = 0; c < 128; ++c) s += pl[c] * Wo[c * 128 + tid];
        mid[tid] = s;
    }
    __syncthreads();
    for (int j = tid; j < 512; j += 256) {
        float s = bout[j];
#pragma unroll 4
        for (int i = 0; i < 128; ++i) s += mid[i] * Wout[i * 512 + j];
        out[bq * 512 + j] = s;
    }
}

// ---------------------------------------------------------------------------
extern "C" void kernel_launch(void* const* d_in, const int* in_sizes, int n_in,
                              void* d_out, int out_size, void* d_ws, size_t ws_size,
                              hipStream_t stream) {
    (void)in_sizes; (void)n_in; (void)out_size; (void)ws_size;
    const float* ohlc = (const float*)d_in[0];
    const float* Wp   = (const float*)d_in[1];  const float* bp   = (const float*)d_in[2];
    const float* Wc1  = (const float*)d_in[3];  const float* bc1  = (const float*)d_in[4];
    const float* Wc2  = (const float*)d_in[5];  const float* bc2  = (const float*)d_in[6];
    const float* Wv1  = (const float*)d_in[7];  const float* bv1  = (const float*)d_in[8];
    const float* Wv2  = (const float*)d_in[9];  const float* bv2  = (const float*)d_in[10];
    const float* Ws1  = (const float*)d_in[11]; const float* bs1  = (const float*)d_in[12];
    const float* Ws2  = (const float*)d_in[13]; const float* bs2  = (const float*)d_in[14];
    const float* Wqkv = (const float*)d_in[15]; const float* bqkv = (const float*)d_in[16];
    const float* Wo   = (const float*)d_in[17]; const float* bo   = (const float*)d_in[18];
    const float* Wout = (const float*)d_in[19]; const float* bout = (const float*)d_in[20];
    float* out = (float*)d_out;
    char* ws = (char*)d_ws;

    const size_t MB8 = 8388608;
    unsigned short* feats = (unsigned short*)(ws);             // later reused as V^T
    unsigned short* hbuf  = (unsigned short*)(ws + MB8);       // later reused as V tmp
    unsigned short* qg    = (unsigned short*)(ws + 2 * MB8);
    unsigned short* kg    = (unsigned short*)(ws + 3 * MB8);
    float*          pooled = (float*)(ws + 4 * MB8);
    unsigned short* wc1t  = (unsigned short*)(ws + 4 * MB8 + 8192);
    unsigned short* wc2t  = wc1t + 8192;
    unsigned short* wv1t  = wc2t + 4096;
    unsigned short* wv2t  = wv1t + 4096;
    unsigned short* ws1t  = wv2t + 1024;
    unsigned short* ws2t  = ws1t + 4096;
    unsigned short* wqkvt = ws2t + 1024;
    unsigned short* vtmp = hbuf;    // free after MLP chain
    unsigned short* vTg  = feats;   // free after qkv_gemm reads it

    prep_kernel<<<288, 256, 0, stream>>>(Wc1, Wc2, Wv1, Wv2, Ws1, Ws2, Wqkv,
                                         wc1t, wc2t, wv1t, wv2t, ws1t, ws2t, wqkvt, pooled);
    embed_kernel<<<128, 256, 0, stream>>>(ohlc, Wp, bp, feats);
    mlp_gemm<128, 64,  true ><<<256, 256, 0, stream>>>(feats, 128, wc1t, bc1, hbuf,       128);
    mlp_gemm<32,  128, false><<<256, 256, 0, stream>>>(hbuf,  128, wc2t, bc2, feats + 64, 128);
    mlp_gemm<64,  64,  true ><<<256, 256, 0, stream>>>(feats, 128, wv1t, bv1, hbuf,       128);
    mlp_gemm<16,  64,  false><<<256, 256, 0, stream>>>(hbuf,  128, wv2t, bv2, feats + 96, 128);
    mlp_gemm<64,  64,  true ><<<256, 256, 0, stream>>>(feats, 128, ws1t, bs1, hbuf,       128);
    mlp_gemm<16,  64,  false><<<256, 256, 0, stream>>>(hbuf,  128, ws2t, bs2, feats + 112, 128);
    qkv_gemm<<<dim3(256, 3), 256, 0, stream>>>(feats, wqkvt, bqkv, qg, kg, vtmp);
    vtrans_kernel<<<2048, 256, 0, stream>>>(vtmp, vTg);
    attn_kernel<<<1024, 256, 0, stream>>>(qg, kg, vTg, pooled);
    head_kernel<<<16, 256, 0, stream>>>(pooled, Wo, bo, Wout, bout, out);
}

// Round 2
// 176.007 us; speedup vs baseline: 1.1614x; 1.1614x over previous
//
#include <hip/hip_runtime.h>

// ---------------------------------------------------------------------------
// PriceGeometryEncoder on MI355X — round 2.
// prep -> fused_mlp (embed + 3 MLP chains, LDS-resident) -> QKV GEMM (+ per-
// (b,h) score-bound via atomicMax) -> flash attention (static-max softmax,
// 1-barrier double-buffered KV staging, V transposed at stage time) -> head.
// out = (mean_t(o) @ Wo + bo) @ Wout + bout (mean commutes), so attention only
// emits column sums of O.
// ---------------------------------------------------------------------------

typedef __attribute__((ext_vector_type(4)))  float f32x4;
typedef __attribute__((ext_vector_type(16))) float f32x16;
typedef __attribute__((ext_vector_type(4)))  short short4v;
typedef __attribute__((ext_vector_type(8)))  short short8v;

static __device__ __forceinline__ unsigned short f2b(float f) {
    unsigned int u = __builtin_bit_cast(unsigned int, f);
    u += 0x7fffu + ((u >> 16) & 1u);       // round-to-nearest-even
    return (unsigned short)(u >> 16);
}

static __device__ __forceinline__ unsigned int cvtpk_bf16(float a, float b) {
    unsigned int r;
    asm volatile("v_cvt_pk_bf16_f32 %0, %1, %2" : "=v"(r) : "v"(a), "v"(b));
    return r;
}

// ---------------------------------------------------------------------------
// K0: weight transposes (f32 -> bf16 [N][K]) + zero pooled + qkmax.
// ---------------------------------------------------------------------------
__global__ __launch_bounds__(256) void prep_kernel(
    const float* Wc1, const float* Wc2, const float* Wv1, const float* Wv2,
    const float* Ws1, const float* Ws2, const float* Wqkv,
    unsigned short* wc1t, unsigned short* wc2t, unsigned short* wv1t,
    unsigned short* wv2t, unsigned short* ws1t, unsigned short* ws2t,
    unsigned short* wqkvt, float* pooled, float* qkmax)
{
    int idx = blockIdx.x * 256 + threadIdx.x;
    if (idx < 8192)  { int n = idx >> 6, kk = idx & 63;  wc1t[idx] = f2b(Wc1[kk*128 + n]); return; }
    idx -= 8192;
    if (idx < 4096)  { int n = idx >> 7, kk = idx & 127; wc2t[idx] = f2b(Wc2[kk*32  + n]); return; }
    idx -= 4096;
    if (idx < 4096)  { int n = idx >> 6, kk = idx & 63;  wv1t[idx] = f2b(Wv1[kk*64  + n]); return; }
    idx -= 4096;
    if (idx < 1024)  { int n = idx >> 6, kk = idx & 63;  wv2t[idx] = f2b(Wv2[kk*16  + n]); return; }
    idx -= 1024;
    if (idx < 4096)  { int n = idx >> 6, kk = idx & 63;  ws1t[idx] = f2b(Ws1[kk*64  + n]); return; }
    idx -= 4096;
    if (idx < 1024)  { int n = idx >> 6, kk = idx & 63;  ws2t[idx] = f2b(Ws2[kk*16  + n]); return; }
    idx -= 1024;
    if (idx < 49152) { int n = idx >> 7, kk = idx & 127; wqkvt[idx] = f2b(Wqkv[kk*384 + n]); return; }
    idx -= 49152;
    if (idx < 2048)  { pooled[idx] = 0.f; return; }
    idx -= 2048;
    if (idx < 128)   qkmax[idx] = 0.f;
}

// ---------------------------------------------------------------------------
// Tile GEMM building block for fused_mlp: wave owns 16 tokens.
// A from LDS (swizzled 16B slots, mask ASL-1); B fragments gathered directly
// from global bf16 [N][K] (L2-resident weights). Output either to Ht LDS
// (ROWB=256, mask 15, scalar bf16 stores) or to global feats columns.
// ---------------------------------------------------------------------------
template<int N, int K, int A_ROWB, bool RELU, bool TO_LDS>
static __device__ __forceinline__ void tile_gemm(
    const char* As, const unsigned short* __restrict__ BT,
    const float* __restrict__ bias, char* Ht,
    unsigned short* __restrict__ gOut, int ocol,
    int m0, int w, int lane)
{
    constexpr int ASL = A_ROWB / 16, NT = N / 16, KS = K / 32;
    int l15 = lane & 15, hi4 = lane >> 4;
    f32x4 acc[NT];
#pragma unroll
    for (int nt = 0; nt < NT; ++nt)
#pragma unroll
        for (int r = 0; r < 4; ++r) acc[nt][r] = 0.f;

#pragma unroll
    for (int ks = 0; ks < KS; ++ks) {
        int slot = ks * 4 + hi4;
        int m = w * 16 + l15;
        short8v af = *(const short8v*)(As + m * A_ROWB + ((slot ^ (m & (ASL - 1))) << 4));
#pragma unroll
        for (int nt = 0; nt < NT; ++nt) {
            int n = nt * 16 + l15;
            short8v bf = *(const short8v*)(BT + (size_t)n * K + slot * 8);
            acc[nt] = __builtin_amdgcn_mfma_f32_16x16x32_bf16(af, bf, acc[nt], 0, 0, 0);
        }
    }
#pragma unroll
    for (int nt = 0; nt < NT; ++nt) {
        int n = nt * 16 + l15;
        float bv = bias[n];
#pragma unroll
        for (int r = 0; r < 4; ++r) {
            int m = w * 16 + hi4 * 4 + r;
            float v = acc[nt][r] + bv;
            if (RELU) v = fmaxf(v, 0.f);
            if (TO_LDS) {
                *(unsigned short*)(Ht + m * 256 + ((((n >> 3) ^ (m & 15))) << 4) + (n & 7) * 2) = f2b(v);
            } else {
                gOut[(size_t)(m0 + m) * 128 + ocol + n] = f2b(v);
            }
        }
    }
}

// ---------------------------------------------------------------------------
// K1: fused embed + curvature/volatility/sr MLP chains. 64 tokens per block,
// 4 waves x 16 tokens. Intermediates in per-wave LDS quadrants -> only the
// one embed barrier; GEMM chain is barrier-free (per-wave DS ordering).
// ---------------------------------------------------------------------------
__global__ __launch_bounds__(256) void fused_mlp(
    const float* __restrict__ ohlc, const float* __restrict__ Wp, const float* __restrict__ bp,
    const unsigned short* __restrict__ wc1t, const float* __restrict__ bc1,
    const unsigned short* __restrict__ wc2t, const float* __restrict__ bc2,
    const unsigned short* __restrict__ wv1t, const float* __restrict__ bv1,
    const unsigned short* __restrict__ wv2t, const float* __restrict__ bv2,
    const unsigned short* __restrict__ ws1t, const float* __restrict__ bs1,
    const unsigned short* __restrict__ ws2t, const float* __restrict__ bs2,
    unsigned short* __restrict__ feats)
{
    __shared__ float wp[256];
    __shared__ float bpl[64];
    __shared__ char Et[64 * 128];    // e tile bf16 [64 tok][64], swizzled (mask 7)
    __shared__ char Ht[64 * 256];    // hidden tile bf16 [64 tok][128], swizzled (mask 15)

    int tid = threadIdx.x;
    int m0 = blockIdx.x * 64;
    wp[tid] = Wp[tid];
    if (tid < 64) bpl[tid] = bp[tid];
    __syncthreads();

    {   // embed: e = ohlc @ Wp + bp; write to Et (A-operand) + global feats[:,0:64]
        int tok = tid >> 2, jq = tid & 3;
        float4 ov = ((const float4*)ohlc)[m0 + tok];
#pragma unroll
        for (int c = 0; c < 2; ++c) {
            int sl = jq * 2 + c;            // 16B slot 0..7
            union { unsigned short us[8]; short8v v; } pk;
#pragma unroll
            for (int jj = 0; jj < 8; ++jj) {
                int j = sl * 8 + jj;
                float e = bpl[j] + ov.x * wp[j] + ov.y * wp[64 + j]
                                 + ov.z * wp[128 + j] + ov.w * wp[192 + j];
                pk.us[jj] = f2b(e);
            }
            *(short8v*)(Et + tok * 128 + ((sl ^ (tok & 7)) << 4)) = pk.v;
            *(short8v*)(feats + (size_t)(m0 + tok) * 128 + sl * 8) = pk.v;
        }
    }
    __syncthreads();

    int lane = tid & 63, w = tid >> 6;
    tile_gemm<128, 64, 128, true,  true >(Et, wc1t, bc1, Ht, feats, 0,   m0, w, lane);
    tile_gemm<32, 128, 256, false, false>(Ht, wc2t, bc2, Ht, feats, 64,  m0, w, lane);
    tile_gemm<64,  64, 128, true,  true >(Et, wv1t, bv1, Ht, feats, 0,   m0, w, lane);
    tile_gemm<16,  64, 256, false, false>(Ht, wv2t, bv2, Ht, feats, 96,  m0, w, lane);
    tile_gemm<64,  64, 128, true,  true >(Et, ws1t, bs1, Ht, feats, 0,   m0, w, lane);
    tile_gemm<16,  64, 256, false, false>(Ht, ws2t, bs2, Ht, feats, 112, m0, w, lane);
}

// ---------------------------------------------------------------------------
// K2: QKV GEMM (M=32768, K=128), blockIdx.y selects q/k/v third.
// q scaled by log2e/sqrt(32). Epilogue also tracks per-(b,h) max|q̂|,max|k|
// via wave-reduce + atomicMax (int bits, values >= 0) -> score bound for attn.
// ---------------------------------------------------------------------------
__global__ __launch_bounds__(256) void qkv_gemm(
    const unsigned short* __restrict__ feats,
    const unsigned short* __restrict__ wqkvt, const float* __restrict__ bqkv,
    unsigned short* __restrict__ qg, unsigned short* __restrict__ kg,
    unsigned short* __restrict__ vg, float* __restrict__ qkmax)
{
    constexpr int ROWB = 256, CPR = 16;
    __shared__ char As[128 * ROWB];
    __shared__ char Bs[128 * ROWB];

    int tid = threadIdx.x;
    int m0 = blockIdx.x * 128;
    int sel = blockIdx.y;
    const unsigned short* BT = wqkvt + (size_t)sel * 128 * 128;

    for (int c = tid; c < 128 * CPR; c += 256) {
        int m = c / CPR, s = c % CPR;
        short8v v = *(const short8v*)(feats + (size_t)(m0 + m) * 128 + s * 8);
        *(short8v*)(As + m * ROWB + ((s ^ (m & 15)) * 16)) = v;
    }
    for (int c = tid; c < 128 * CPR; c += 256) {
        int n = c / CPR, s = c % CPR;
        short8v v = *(const short8v*)(BT + (size_t)n * 128 + s * 8);
        *(short8v*)(Bs + n * ROWB + ((s ^ (n & 15)) * 16)) = v;
    }
    __syncthreads();

    int lane = tid & 63, w = tid >> 6;
    int l15 = lane & 15, hi4 = lane >> 4;

    f32x4 acc[2][8];
#pragma unroll
    for (int mt = 0; mt < 2; ++mt)
#pragma unroll
        for (int nt = 0; nt < 8; ++nt)
#pragma unroll
            for (int r = 0; r < 4; ++r) acc[mt][nt][r] = 0.f;

#pragma unroll
    for (int ks = 0; ks < 4; ++ks) {
        int slot = ks * 4 + hi4;
        short8v af[2];
#pragma unroll
        for (int mt = 0; mt < 2; ++mt) {
            int m = w * 32 + mt * 16 + l15;
            af[mt] = *(const short8v*)(As + m * ROWB + ((slot ^ (m & 15)) * 16));
        }
#pragma unroll
        for (int nt = 0; nt < 8; ++nt) {
            int n = nt * 16 + l15;
            short8v bf = *(const short8v*)(Bs + n * ROWB + ((slot ^ (n & 15)) * 16));
            acc[0][nt] = __builtin_amdgcn_mfma_f32_16x16x32_bf16(af[0], bf, acc[0][nt], 0, 0, 0);
            acc[1][nt] = __builtin_amdgcn_mfma_f32_16x16x32_bf16(af[1], bf, acc[1][nt], 0, 0, 0);
        }
    }

    const float QSCALE = 1.4426950408889634f * 0.17677669529663687f; // log2e/sqrt(32)
    float amax[4] = {0.f, 0.f, 0.f, 0.f};
#pragma unroll
    for (int mt = 0; mt < 2; ++mt)
#pragma unroll
        for (int nt = 0; nt < 8; ++nt) {
            int n = nt * 16 + l15;
            float bv = bqkv[sel * 128 + n];
#pragma unroll
            for (int r = 0; r < 4; ++r) {
                int t = m0 + w * 32 + mt * 16 + hi4 * 4 + r;
                float v = acc[mt][nt][r] + bv;
                int b = t >> 11, tp = t & 2047;
                int h = n >> 5, dh = n & 31;
                size_t o = ((size_t)((b * 4 + h) * 2048 + tp)) * 32 + dh;
                if (sel == 0) {
                    float sv = v * QSCALE;
                    qg[o] = f2b(sv);
                    amax[nt >> 1] = fmaxf(amax[nt >> 1], fabsf(sv));
                } else if (sel == 1) {
                    kg[o] = f2b(v);
                    amax[nt >> 1] = fmaxf(amax[nt >> 1], fabsf(v));
                } else {
                    vg[o] = f2b(v);
                }
            }
        }

    if (sel < 2) {
        int b = m0 >> 11;
#pragma unroll
        for (int g = 0; g < 4; ++g) {
            float mv = amax[g];
            mv = fmaxf(mv, __shfl_xor(mv, 1));  mv = fmaxf(mv, __shfl_xor(mv, 2));
            mv = fmaxf(mv, __shfl_xor(mv, 4));  mv = fmaxf(mv, __shfl_xor(mv, 8));
            mv = fmaxf(mv, __shfl_xor(mv, 16)); mv = fmaxf(mv, __shfl_xor(mv, 32));
            if (lane == 0)
                atomicMax((int*)(qkmax + sel * 64 + b * 4 + g), __float_as_int(mv));
        }
    }
}

// ---------------------------------------------------------------------------
// K3: flash attention, static-max softmax (M0 = 32*qmax*kmax bounds all
// scores in log2 domain; constant offset cancels in O/Σp). Double-buffered
// KV staging with ONE barrier per 64-key tile; V transposed into LDS at
// stage time from its natural [t][dh] layout. Column sums of O/lsum go to
// pooled[b][h*32+dh] via atomicAdd.
// ---------------------------------------------------------------------------
__global__ __launch_bounds__(256) void attn_kernel(
    const unsigned short* __restrict__ qg, const unsigned short* __restrict__ kg,
    const unsigned short* __restrict__ vg, const float* __restrict__ qkmax,
    float* __restrict__ pooled)
{
    __shared__ char Ks[2][64 * 72];   // [64 keys][32 kd], 72B stride
    __shared__ char Vs[2][32 * 128];  // [32 dh][64 keys], XOR-swizzled 16B slots

    int tid = threadIdx.x, bid = blockIdx.x;
    int bh = bid >> 4, qb = bid & 15;
    int b = bh >> 2, h = bh & 3;
    int lane = tid & 63, w = tid >> 6;
    int l31 = lane & 31, hi = lane >> 5;
    int q0 = qb * 128 + w * 32;

    const unsigned short* qrow = qg + ((size_t)(bh * 2048 + q0 + l31)) * 32;
    short8v Qf0 = *(const short8v*)(qrow + hi * 8);        // kd 0..15
    short8v Qf1 = *(const short8v*)(qrow + 16 + hi * 8);   // kd 16..31

    float M0 = 32.0f * qkmax[bh] * qkmax[64 + bh];

    f32x16 accO;
#pragma unroll
    for (int r = 0; r < 16; ++r) accO[r] = 0.f;
    float lsum = 0.f;

    int skey = tid >> 2, sseg = tid & 3;       // K staging
    int vtok = tid & 63, vd0 = (tid >> 6) * 8; // V staging (transpose)
    const unsigned short* kbase = kg + (size_t)bh * 2048 * 32;
    const unsigned short* vbase = vg + (size_t)bh * 2048 * 32;

    auto load_tile = [&](int kt, short8v& kr, short8v& vr) {
        int k0 = kt * 64;
        kr = *(const short8v*)(kbase + (size_t)(k0 + skey) * 32 + sseg * 8);
        vr = *(const short8v*)(vbase + (size_t)(k0 + vtok) * 32 + vd0);
    };
    auto store_tile = [&](int bufi, short8v kr, short8v vr) {
        union { short8v v; short4v h2[2]; } ku; ku.v = kr;
        char* kd = Ks[bufi] + skey * 72 + sseg * 16;
        *(short4v*)(kd)     = ku.h2[0];
        *(short4v*)(kd + 8) = ku.h2[1];
        union { short8v v; unsigned short us[8]; } vu; vu.v = vr;
#pragma unroll
        for (int j = 0; j < 8; ++j) {
            int dh = vd0 + j;
            *(unsigned short*)(Vs[bufi] + dh * 128 +
                ((((vtok >> 3) ^ (dh & 7))) << 4) + (vtok & 7) * 2) = vu.us[j];
        }
    };
    auto compute = [&](int bufi) {
#pragma unroll
        for (int sub = 0; sub < 2; ++sub) {
            const char* arow = Ks[bufi] + (sub * 32 + l31) * 72 + hi * 16;
            union { short4v h2[2]; short8v v; } a0, a1;
            a0.h2[0] = *(const short4v*)(arow);
            a0.h2[1] = *(const short4v*)(arow + 8);
            a1.h2[0] = *(const short4v*)(arow + 32);
            a1.h2[1] = *(const short4v*)(arow + 40);

            f32x16 s;
#pragma unroll
            for (int r = 0; r < 16; ++r) s[r] = 0.f;
            s = __builtin_amdgcn_mfma_f32_32x32x16_bf16(a0.v, Qf0, s, 0, 0, 0);
            s = __builtin_amdgcn_mfma_f32_32x32x16_bf16(a1.v, Qf1, s, 0, 0, 0);

            float p[16];
            float ps = 0.f;
#pragma unroll
            for (int r = 0; r < 16; ++r) {
                float pv = __builtin_amdgcn_exp2f(s[r] - M0);
                p[r] = pv; ps += pv;
            }
            lsum += ps;

#pragma unroll
            for (int c2 = 0; c2 < 2; ++c2) {
                unsigned int wa = cvtpk_bf16(p[c2 * 8 + 0], p[c2 * 8 + 1]);
                unsigned int wb = cvtpk_bf16(p[c2 * 8 + 2], p[c2 * 8 + 3]);
                unsigned int wc = cvtpk_bf16(p[c2 * 8 + 4], p[c2 * 8 + 5]);
                unsigned int wd = cvtpk_bf16(p[c2 * 8 + 6], p[c2 * 8 + 7]);
                asm volatile("v_permlane32_swap_b32 %0, %1" : "+v"(wa), "+v"(wc));
                asm volatile("v_permlane32_swap_b32 %0, %1" : "+v"(wb), "+v"(wd));
                union { unsigned int u[4]; short8v v; } pf;
                pf.u[0] = wa; pf.u[1] = wb; pf.u[2] = wc; pf.u[3] = wd;

                short8v vf = *(const short8v*)(Vs[bufi] + l31 * 128 +
                              ((sub * 64 + c2 * 32 + hi * 16) ^ ((l31 & 7) << 4)));
                accO = __builtin_amdgcn_mfma_f32_32x32x16_bf16(vf, pf.v, accO, 0, 0, 0);
            }
        }
    };

    short8v ka, va, kb, vb;
    load_tile(0, ka, va);
    store_tile(0, ka, va);
    load_tile(1, kb, vb);
    __syncthreads();

    for (int kt = 0; kt < 32; kt += 2) {
        store_tile(1, kb, vb);                       // tile kt+1 (always exists)
        if (kt + 2 < 32) load_tile(kt + 2, ka, va);
        compute(0);                                  // tile kt
        __syncthreads();
        if (kt + 2 < 32) store_tile(0, ka, va);      // tile kt+2
        if (kt + 3 < 32) load_tile(kt + 3, kb, vb);
        compute(1);                                  // tile kt+1
        __syncthreads();
    }

    // per-q normalization, then sum over this wave's 32 q rows -> pooled
    lsum += __shfl_xor(lsum, 32);
    float inv = 1.0f / lsum;
#pragma unroll
    for (int r = 0; r < 16; ++r) {
        float v = accO[r] * inv;
        v += __shfl_xor(v, 1); v += __shfl_xor(v, 2); v += __shfl_xor(v, 4);
        v += __shfl_xor(v, 8); v += __shfl_xor(v, 16);
        if (l31 == 0) {
            int dh = (r & 3) + 8 * (r >> 2) + 4 * hi;
            atomicAdd(pooled + b * 128 + h * 32 + dh, v);
        }
    }
}

// ---------------------------------------------------------------------------
// K4: out[b] = (pooled[b]/2048 @ Wo + bo) @ Wout + bout   (f32, tiny)
// ---------------------------------------------------------------------------
__global__ __launch_bounds__(256) void head_kernel(
    const float* __restrict__ pooled, const float* __restrict__ Wo,
    const float* __restrict__ bo, const float* __restrict__ Wout,
    const float* __restrict__ bout, float* __restrict__ out)
{
    int bq = blockIdx.x, tid = threadIdx.x;
    __shared__ float pl[128], mid[128];
    if (tid < 128) pl[tid] = pooled[bq * 128 + tid] * (1.f / 2048.f);
    __syncthreads();
    if (tid < 128) {
        float s = bo[tid];
#pragma unroll 4
        for (int c = 0; c < 128; ++c) s += pl[c] * Wo[c * 128 + tid];
        mid[tid] = s;
    }
    __syncthreads();
    for (int j = tid; j < 512; j += 256) {
        float s = bout[j];
#pragma unroll 4
        for (int i = 0; i < 128; ++i) s += mid[i] * Wout[i * 512 + j];
        out[bq * 512 + j] = s;
    }
}

// ---------------------------------------------------------------------------
extern "C" void kernel_launch(void* const* d_in, const int* in_sizes, int n_in,
                              void* d_out, int out_size, void* d_ws, size_t ws_size,
                              hipStream_t stream) {
    (void)in_sizes; (void)n_in; (void)out_size; (void)ws_size;
    const float* ohlc = (const float*)d_in[0];
    const float* Wp   = (const float*)d_in[1];  const float* bp   = (const float*)d_in[2];
    const float* Wc1  = (const float*)d_in[3];  const float* bc1  = (const float*)d_in[4];
    const float* Wc2  = (const float*)d_in[5];  const float* bc2  = (const float*)d_in[6];
    const float* Wv1  = (const float*)d_in[7];  const float* bv1  = (const float*)d_in[8];
    const float* Wv2  = (const float*)d_in[9];  const float* bv2  = (const float*)d_in[10];
    const float* Ws1  = (const float*)d_in[11]; const float* bs1  = (const float*)d_in[12];
    const float* Ws2  = (const float*)d_in[13]; const float* bs2  = (const float*)d_in[14];
    const float* Wqkv = (const float*)d_in[15]; const float* bqkv = (const float*)d_in[16];
    const float* Wo   = (const float*)d_in[17]; const float* bo   = (const float*)d_in[18];
    const float* Wout = (const float*)d_in[19]; const float* bout = (const float*)d_in[20];
    float* out = (float*)d_out;
    char* ws = (char*)d_ws;

    const size_t MB8 = 8388608;
    unsigned short* feats = (unsigned short*)(ws);
    unsigned short* qg    = (unsigned short*)(ws + 1 * MB8);
    unsigned short* kg    = (unsigned short*)(ws + 2 * MB8);
    unsigned short* vg    = (unsigned short*)(ws + 3 * MB8);
    float*          pooled = (float*)(ws + 4 * MB8);
    float*          qkmax  = (float*)(ws + 4 * MB8 + 8192);
    unsigned short* wc1t  = (unsigned short*)(ws + 4 * MB8 + 8192 + 512);
    unsigned short* wc2t  = wc1t + 8192;
    unsigned short* wv1t  = wc2t + 4096;
    unsigned short* wv2t  = wv1t + 4096;
    unsigned short* ws1t  = wv2t + 1024;
    unsigned short* ws2t  = ws1t + 4096;
    unsigned short* wqkvt = ws2t + 1024;

    prep_kernel<<<289, 256, 0, stream>>>(Wc1, Wc2, Wv1, Wv2, Ws1, Ws2, Wqkv,
                                         wc1t, wc2t, wv1t, wv2t, ws1t, ws2t, wqkvt,
                                         pooled, qkmax);
    fused_mlp<<<512, 256, 0, stream>>>(ohlc, Wp, bp, wc1t, bc1, wc2t, bc2,
                                       wv1t, bv1, wv2t, bv2, ws1t, bs1, ws2t, bs2, feats);
    qkv_gemm<<<dim3(256, 3), 256, 0, stream>>>(feats, wqkvt, bqkv, qg, kg, vg, qkmax);
    attn_kernel<<<1024, 256, 0, stream>>>(qg, kg, vg, qkmax, pooled);
    head_kernel<<<16, 256, 0, stream>>>(pooled, Wo, bo, Wout, bout, out);
}

// Round 3
// 155.079 us; speedup vs baseline: 1.3181x; 1.1350x over previous
//
#include <hip/hip_runtime.h>

// ---------------------------------------------------------------------------
// PriceGeometryEncoder on MI355X — round 3.
// prep(small) + wqkv_trans(tiled) -> fused_mlp -> QKV GEMM (LDS-bounce
// coalesced epilogue, writes q,k natural + V TRANSPOSED, per-(b,h) score
// bound) -> flash attention (static-max softmax, K in registers from L2,
// V staged reg->LDS 4-buffer ring, ONE raw s_barrier per tile, XCD-swizzled
// grid) -> head.  out = (mean_t(o) @ Wo + bo) @ Wout + bout.
// ---------------------------------------------------------------------------

typedef __attribute__((ext_vector_type(4)))  float f32x4;
typedef __attribute__((ext_vector_type(16))) float f32x16;
typedef __attribute__((ext_vector_type(4)))  short short4v;
typedef __attribute__((ext_vector_type(8)))  short short8v;

static __device__ __forceinline__ unsigned short f2b(float f) {
    unsigned int u = __builtin_bit_cast(unsigned int, f);
    u += 0x7fffu + ((u >> 16) & 1u);       // round-to-nearest-even
    return (unsigned short)(u >> 16);
}

static __device__ __forceinline__ unsigned int cvtpk_bf16(float a, float b) {
    unsigned int r;
    asm volatile("v_cvt_pk_bf16_f32 %0, %1, %2" : "=v"(r) : "v"(a), "v"(b));
    return r;
}

// ---------------------------------------------------------------------------
// K0a: small weight transposes (f32 -> bf16 [N][K]) + zero pooled + qkmax.
// ---------------------------------------------------------------------------
__global__ __launch_bounds__(256) void prep_kernel(
    const float* Wc1, const float* Wc2, const float* Wv1, const float* Wv2,
    const float* Ws1, const float* Ws2,
    unsigned short* wc1t, unsigned short* wc2t, unsigned short* wv1t,
    unsigned short* wv2t, unsigned short* ws1t, unsigned short* ws2t,
    float* pooled, float* qkmax)
{
    int idx = blockIdx.x * 256 + threadIdx.x;
    if (idx < 8192)  { int n = idx >> 6, kk = idx & 63;  wc1t[idx] = f2b(Wc1[kk*128 + n]); return; }
    idx -= 8192;
    if (idx < 4096)  { int n = idx >> 7, kk = idx & 127; wc2t[idx] = f2b(Wc2[kk*32  + n]); return; }
    idx -= 4096;
    if (idx < 4096)  { int n = idx >> 6, kk = idx & 63;  wv1t[idx] = f2b(Wv1[kk*64  + n]); return; }
    idx -= 4096;
    if (idx < 1024)  { int n = idx >> 6, kk = idx & 63;  wv2t[idx] = f2b(Wv2[kk*16  + n]); return; }
    idx -= 1024;
    if (idx < 4096)  { int n = idx >> 6, kk = idx & 63;  ws1t[idx] = f2b(Ws1[kk*64  + n]); return; }
    idx -= 4096;
    if (idx < 1024)  { int n = idx >> 6, kk = idx & 63;  ws2t[idx] = f2b(Ws2[kk*16  + n]); return; }
    idx -= 1024;
    if (idx < 2048)  { pooled[idx] = 0.f; return; }
    idx -= 2048;
    if (idx < 128)   qkmax[idx] = 0.f;
}

// ---------------------------------------------------------------------------
// K0b: Wqkv [128 k][384 n] f32 -> wqkvt [384 n][128 k] bf16, 32x32 LDS tiles.
// ---------------------------------------------------------------------------
__global__ __launch_bounds__(256) void wqkv_trans(
    const float* __restrict__ W, unsigned short* __restrict__ outT)
{
    __shared__ float tile[32][33];
    int bidn = blockIdx.x % 12, bidk = blockIdx.x / 12;
    int n0 = bidn * 32, k0 = bidk * 32;
    int tid = threadIdx.x;
    {
        int r = tid >> 3, cq = tid & 7;
        float4 v = *(const float4*)(W + (size_t)(k0 + r) * 384 + n0 + cq * 4);
        tile[r][cq*4+0] = v.x; tile[r][cq*4+1] = v.y;
        tile[r][cq*4+2] = v.z; tile[r][cq*4+3] = v.w;
    }
    __syncthreads();
    {
        int nr = tid >> 3, kq = tid & 7;
        union { unsigned short us[4]; short4v v; } pk;
#pragma unroll
        for (int j = 0; j < 4; ++j) pk.us[j] = f2b(tile[kq*4+j][nr]);
        *(short4v*)(outT + (size_t)(n0 + nr) * 128 + k0 + kq * 4) = pk.v;
    }
}

// ---------------------------------------------------------------------------
// Tile GEMM building block for fused_mlp (unchanged from round 2).
// ---------------------------------------------------------------------------
template<int N, int K, int A_ROWB, bool RELU, bool TO_LDS>
static __device__ __forceinline__ void tile_gemm(
    const char* As, const unsigned short* __restrict__ BT,
    const float* __restrict__ bias, char* Ht,
    unsigned short* __restrict__ gOut, int ocol,
    int m0, int w, int lane)
{
    constexpr int ASL = A_ROWB / 16, NT = N / 16, KS = K / 32;
    int l15 = lane & 15, hi4 = lane >> 4;
    f32x4 acc[NT];
#pragma unroll
    for (int nt = 0; nt < NT; ++nt)
#pragma unroll
        for (int r = 0; r < 4; ++r) acc[nt][r] = 0.f;

#pragma unroll
    for (int ks = 0; ks < KS; ++ks) {
        int slot = ks * 4 + hi4;
        int m = w * 16 + l15;
        short8v af = *(const short8v*)(As + m * A_ROWB + ((slot ^ (m & (ASL - 1))) << 4));
#pragma unroll
        for (int nt = 0; nt < NT; ++nt) {
            int n = nt * 16 + l15;
            short8v bf = *(const short8v*)(BT + (size_t)n * K + slot * 8);
            acc[nt] = __builtin_amdgcn_mfma_f32_16x16x32_bf16(af, bf, acc[nt], 0, 0, 0);
        }
    }
#pragma unroll
    for (int nt = 0; nt < NT; ++nt) {
        int n = nt * 16 + l15;
        float bv = bias[n];
#pragma unroll
        for (int r = 0; r < 4; ++r) {
            int m = w * 16 + hi4 * 4 + r;
            float v = acc[nt][r] + bv;
            if (RELU) v = fmaxf(v, 0.f);
            if (TO_LDS) {
                *(unsigned short*)(Ht + m * 256 + ((((n >> 3) ^ (m & 15))) << 4) + (n & 7) * 2) = f2b(v);
            } else {
                gOut[(size_t)(m0 + m) * 128 + ocol + n] = f2b(v);
            }
        }
    }
}

// ---------------------------------------------------------------------------
// K1: fused embed + 3 MLP chains (unchanged from round 2).
// ---------------------------------------------------------------------------
__global__ __launch_bounds__(256) void fused_mlp(
    const float* __restrict__ ohlc, const float* __restrict__ Wp, const float* __restrict__ bp,
    const unsigned short* __restrict__ wc1t, const float* __restrict__ bc1,
    const unsigned short* __restrict__ wc2t, const float* __restrict__ bc2,
    const unsigned short* __restrict__ wv1t, const float* __restrict__ bv1,
    const unsigned short* __restrict__ wv2t, const float* __restrict__ bv2,
    const unsigned short* __restrict__ ws1t, const float* __restrict__ bs1,
    const unsigned short* __restrict__ ws2t, const float* __restrict__ bs2,
    unsigned short* __restrict__ feats)
{
    __shared__ float wp[256];
    __shared__ float bpl[64];
    __shared__ char Et[64 * 128];
    __shared__ char Ht[64 * 256];

    int tid = threadIdx.x;
    int m0 = blockIdx.x * 64;
    wp[tid] = Wp[tid];
    if (tid < 64) bpl[tid] = bp[tid];
    __syncthreads();

    {
        int tok = tid >> 2, jq = tid & 3;
        float4 ov = ((const float4*)ohlc)[m0 + tok];
#pragma unroll
        for (int c = 0; c < 2; ++c) {
            int sl = jq * 2 + c;
            union { unsigned short us[8]; short8v v; } pk;
#pragma unroll
            for (int jj = 0; jj < 8; ++jj) {
                int j = sl * 8 + jj;
                float e = bpl[j] + ov.x * wp[j] + ov.y * wp[64 + j]
                                 + ov.z * wp[128 + j] + ov.w * wp[192 + j];
                pk.us[jj] = f2b(e);
            }
            *(short8v*)(Et + tok * 128 + ((sl ^ (tok & 7)) << 4)) = pk.v;
            *(short8v*)(feats + (size_t)(m0 + tok) * 128 + sl * 8) = pk.v;
        }
    }
    __syncthreads();

    int lane = tid & 63, w = tid >> 6;
    tile_gemm<128, 64, 128, true,  true >(Et, wc1t, bc1, Ht, feats, 0,   m0, w, lane);
    tile_gemm<32, 128, 256, false, false>(Ht, wc2t, bc2, Ht, feats, 64,  m0, w, lane);
    tile_gemm<64,  64, 128, true,  true >(Et, wv1t, bv1, Ht, feats, 0,   m0, w, lane);
    tile_gemm<16,  64, 256, false, false>(Ht, wv2t, bv2, Ht, feats, 96,  m0, w, lane);
    tile_gemm<64,  64, 128, true,  true >(Et, ws1t, bs1, Ht, feats, 0,   m0, w, lane);
    tile_gemm<16,  64, 256, false, false>(Ht, ws2t, bs2, Ht, feats, 112, m0, w, lane);
}

// ---------------------------------------------------------------------------
// K2: QKV GEMM. sel=0/1 (q,k): LDS-bounce epilogue -> coalesced b128 stores
// into [bh][t][32]; amax via wave-reduce + atomicMax. sel=2 (v): packed-b64
// stores straight into TRANSPOSED vT [bh][dh][t].
// ---------------------------------------------------------------------------
__global__ __launch_bounds__(256) void qkv_gemm(
    const unsigned short* __restrict__ feats,
    const unsigned short* __restrict__ wqkvt, const float* __restrict__ bqkv,
    unsigned short* __restrict__ qg, unsigned short* __restrict__ kg,
    unsigned short* __restrict__ vTg, float* __restrict__ qkmax)
{
    constexpr int ROWB = 256, CPR = 16;
    __shared__ short8v smemv[4096];          // 64 KiB
    char* As = (char*)smemv;
    char* Bs = (char*)smemv + 32768;

    int tid = threadIdx.x;
    int m0 = blockIdx.x * 128;
    int sel = blockIdx.y;
    const unsigned short* BT = wqkvt + (size_t)sel * 128 * 128;

    for (int c = tid; c < 128 * CPR; c += 256) {
        int m = c / CPR, s = c % CPR;
        short8v v = *(const short8v*)(feats + (size_t)(m0 + m) * 128 + s * 8);
        *(short8v*)(As + m * ROWB + ((s ^ (m & 15)) * 16)) = v;
    }
    for (int c = tid; c < 128 * CPR; c += 256) {
        int n = c / CPR, s = c % CPR;
        short8v v = *(const short8v*)(BT + (size_t)n * 128 + s * 8);
        *(short8v*)(Bs + n * ROWB + ((s ^ (n & 15)) * 16)) = v;
    }
    __syncthreads();

    int lane = tid & 63, w = tid >> 6;
    int l15 = lane & 15, hi4 = lane >> 4;

    f32x4 acc[2][8];
#pragma unroll
    for (int mt = 0; mt < 2; ++mt)
#pragma unroll
        for (int nt = 0; nt < 8; ++nt)
#pragma unroll
            for (int r = 0; r < 4; ++r) acc[mt][nt][r] = 0.f;

#pragma unroll
    for (int ks = 0; ks < 4; ++ks) {
        int slot = ks * 4 + hi4;
        short8v af[2];
#pragma unroll
        for (int mt = 0; mt < 2; ++mt) {
            int m = w * 32 + mt * 16 + l15;
            af[mt] = *(const short8v*)(As + m * ROWB + ((slot ^ (m & 15)) * 16));
        }
#pragma unroll
        for (int nt = 0; nt < 8; ++nt) {
            int n = nt * 16 + l15;
            short8v bf = *(const short8v*)(Bs + n * ROWB + ((slot ^ (n & 15)) * 16));
            acc[0][nt] = __builtin_amdgcn_mfma_f32_16x16x32_bf16(af[0], bf, acc[0][nt], 0, 0, 0);
            acc[1][nt] = __builtin_amdgcn_mfma_f32_16x16x32_bf16(af[1], bf, acc[1][nt], 0, 0, 0);
        }
    }

    const float QSCALE = 1.4426950408889634f * 0.17677669529663687f; // log2e/sqrt(32)
    int b = m0 >> 11, tp0 = m0 & 2047;

    if (sel == 2) {
        // direct transposed stores: vT[bh][dh][t], 4 consecutive t packed b64
#pragma unroll
        for (int mt = 0; mt < 2; ++mt)
#pragma unroll
            for (int nt = 0; nt < 8; ++nt) {
                int n = nt * 16 + l15;
                float bv = bqkv[256 + n];
                int h = n >> 5, dh = n & 31;
                float v0 = acc[mt][nt][0] + bv, v1 = acc[mt][nt][1] + bv;
                float v2 = acc[mt][nt][2] + bv, v3 = acc[mt][nt][3] + bv;
                uint2 pk;
                pk.x = cvtpk_bf16(v0, v1);
                pk.y = cvtpk_bf16(v2, v3);
                int t = tp0 + w * 32 + mt * 16 + hi4 * 4;
                *(uint2*)(vTg + ((size_t)(b * 4 + h) * 32 + dh) * 2048 + t) = pk;
            }
    } else {
        float amax[4] = {0.f, 0.f, 0.f, 0.f};
        float scale = (sel == 0) ? QSCALE : 1.0f;
#pragma unroll
        for (int mt = 0; mt < 2; ++mt)
#pragma unroll
            for (int nt = 0; nt < 8; ++nt) {
                int n = nt * 16 + l15;
                float bv = bqkv[sel * 128 + n];
#pragma unroll
                for (int r = 0; r < 4; ++r) {
                    float v = (acc[mt][nt][r] + bv) * scale;
                    amax[nt >> 1] = fmaxf(amax[nt >> 1], fabsf(v));
                    int m = w * 32 + mt * 16 + hi4 * 4 + r;
                    // bounce: [m][n] bf16, 256B rows, 16B-slot XOR swizzle
                    *(unsigned short*)(As + m * 256 + (((n >> 3) ^ (m & 7)) << 4) + (n & 7) * 2) = f2b(v);
                }
            }
#pragma unroll
        for (int g = 0; g < 4; ++g) {
            float mv = amax[g];
            mv = fmaxf(mv, __shfl_xor(mv, 1));  mv = fmaxf(mv, __shfl_xor(mv, 2));
            mv = fmaxf(mv, __shfl_xor(mv, 4));  mv = fmaxf(mv, __shfl_xor(mv, 8));
            mv = fmaxf(mv, __shfl_xor(mv, 16)); mv = fmaxf(mv, __shfl_xor(mv, 32));
            if (lane == 0)
                atomicMax((int*)(qkmax + sel * 64 + b * 4 + g), __float_as_int(mv));
        }
        __syncthreads();
        unsigned short* og = (sel == 0) ? qg : kg;
#pragma unroll
        for (int it = 0; it < 8; ++it) {
            int ch = it * 256 + tid;
            int m = ch >> 4, c = ch & 15;
            short8v vv = *(const short8v*)(As + m * 256 + ((c ^ (m & 7)) << 4));
            int h = c >> 2, dq = c & 3;
            *(short8v*)(og + ((size_t)(b * 4 + h) * 2048 + tp0 + m) * 32 + dq * 8) = vv;
        }
    }
}

// ---------------------------------------------------------------------------
// K3: flash attention. bh = bid&63 (XCD-locality swizzle: all 16 q-blocks of
// a (b,h) share one XCD's L2). K fragments register-double-buffered straight
// from global; V staged reg->LDS into a 4-buffer ring (linear b128 write,
// XOR-swizzled slots for bank-balanced reads); ONE raw s_barrier + lgkmcnt(0)
// per tile (vmcnt prefetches survive the barrier). Static-max softmax with
// -M0 folded into MFMA C-init.
// ---------------------------------------------------------------------------
__global__ __launch_bounds__(256) void attn_kernel(
    const unsigned short* __restrict__ qg, const unsigned short* __restrict__ kg,
    const unsigned short* __restrict__ vTg, const float* __restrict__ qkmax,
    float* __restrict__ pooled)
{
    __shared__ short8v VsBuf[4 * 256];       // 4 x 4 KiB V tiles
    char* Vs = (char*)VsBuf;

    int tid = threadIdx.x, bid = blockIdx.x;
    int bh = bid & 63, qb = bid >> 6;
    int b = bh >> 2;
    int lane = tid & 63, w = tid >> 6;
    int l31 = lane & 31, hi = lane >> 5;
    int q0 = qb * 128 + w * 32;

    const unsigned short* qrow = qg + ((size_t)bh * 2048 + q0 + l31) * 32;
    short8v Qf0 = *(const short8v*)(qrow + hi * 8);        // kd 0..15
    short8v Qf1 = *(const short8v*)(qrow + 16 + hi * 8);   // kd 16..31

    float negM0 = -(32.0f * qkmax[bh] * qkmax[64 + bh]);

    f32x16 accO;
#pragma unroll
    for (int r = 0; r < 16; ++r) accO[r] = 0.f;
    float lsum = 0.f;

    // K per-lane base: row l31 (+32 for sub1), 16B col hi*16 (+32 for kd>=16)
    const char* kp = (const char*)(kg + (size_t)bh * 2048 * 32) + (size_t)l31 * 64 + hi * 16;
    // V per-lane src: dh = w*8 + (lane>>3); phys slot p = lane&7 holds logical p^(dh&7)
    int vdh = w * 8 + (lane >> 3);
    const char* vp = (const char*)(vTg + ((size_t)bh * 32 + vdh) * 2048) +
                     (((lane & 7) ^ (vdh & 7)) << 4);
    int vdst = (w * 64 + lane) * 16;         // linear LDS dest within buffer

    auto step = [&](int t, short8v (&kC)[4], short8v& vC,
                    short8v (&kN)[4], short8v& vN, char* bufp) {
        if (t < 31) {
            const char* p = kp + (size_t)(t + 1) * 4096;
            kN[0] = *(const short8v*)(p);
            kN[1] = *(const short8v*)(p + 32);
            kN[2] = *(const short8v*)(p + 2048);
            kN[3] = *(const short8v*)(p + 2080);
            vN = *(const short8v*)(vp + (size_t)(t + 1) * 128);
        }
        *(short8v*)(bufp + vdst) = vC;       // compiler auto-waits vmcnt for vC
        asm volatile("s_waitcnt lgkmcnt(0)" ::: "memory");
        __builtin_amdgcn_s_barrier();
        asm volatile("" ::: "memory");
#pragma unroll
        for (int sub = 0; sub < 2; ++sub) {
            f32x16 s;
#pragma unroll
            for (int r = 0; r < 16; ++r) s[r] = negM0;
            s = __builtin_amdgcn_mfma_f32_32x32x16_bf16(kC[sub * 2 + 0], Qf0, s, 0, 0, 0);
            s = __builtin_amdgcn_mfma_f32_32x32x16_bf16(kC[sub * 2 + 1], Qf1, s, 0, 0, 0);
            float p_[16];
            float ps = 0.f;
#pragma unroll
            for (int r = 0; r < 16; ++r) {
                p_[r] = __builtin_amdgcn_exp2f(s[r]);
                ps += p_[r];
            }
            lsum += ps;
#pragma unroll
            for (int c2 = 0; c2 < 2; ++c2) {
                unsigned int wa = cvtpk_bf16(p_[c2 * 8 + 0], p_[c2 * 8 + 1]);
                unsigned int wb = cvtpk_bf16(p_[c2 * 8 + 2], p_[c2 * 8 + 3]);
                unsigned int wc = cvtpk_bf16(p_[c2 * 8 + 4], p_[c2 * 8 + 5]);
                unsigned int wd = cvtpk_bf16(p_[c2 * 8 + 6], p_[c2 * 8 + 7]);
                asm volatile("v_permlane32_swap_b32 %0, %1" : "+v"(wa), "+v"(wc));
                asm volatile("v_permlane32_swap_b32 %0, %1" : "+v"(wb), "+v"(wd));
                union { unsigned int u[4]; short8v v; } pf;
                pf.u[0] = wa; pf.u[1] = wb; pf.u[2] = wc; pf.u[3] = wd;

                short8v vf = *(const short8v*)(bufp + l31 * 128 +
                              (((sub * 4 + c2 * 2 + hi) ^ (l31 & 7)) << 4));
                accO = __builtin_amdgcn_mfma_f32_32x32x16_bf16(vf, pf.v, accO, 0, 0, 0);
            }
        }
    };

    short8v kE[4], kO[4], vE, vO;
    {
        kE[0] = *(const short8v*)(kp);
        kE[1] = *(const short8v*)(kp + 32);
        kE[2] = *(const short8v*)(kp + 2048);
        kE[3] = *(const short8v*)(kp + 2080);
        vE = *(const short8v*)(vp);
    }
#pragma unroll 1
    for (int g = 0; g < 8; ++g) {
        int t0 = g * 4;
        step(t0 + 0, kE, vE, kO, vO, Vs + 0 * 4096);
        step(t0 + 1, kO, vO, kE, vE, Vs + 1 * 4096);
        step(t0 + 2, kE, vE, kO, vO, Vs + 2 * 4096);
        step(t0 + 3, kO, vO, kE, vE, Vs + 3 * 4096);
    }

    // per-q normalization, then sum over this wave's 32 q rows -> pooled
    lsum += __shfl_xor(lsum, 32);
    float inv = 1.0f / lsum;
#pragma unroll
    for (int r = 0; r < 16; ++r) {
        float v = accO[r] * inv;
        v += __shfl_xor(v, 1); v += __shfl_xor(v, 2); v += __shfl_xor(v, 4);
        v += __shfl_xor(v, 8); v += __shfl_xor(v, 16);
        if (l31 == 0) {
            int dh = (r & 3) + 8 * (r >> 2) + 4 * hi;
            atomicAdd(pooled + b * 128 + (bh & 3) * 32 + dh, v);
        }
    }
}

// ---------------------------------------------------------------------------
// K4: out[b] = (pooled[b]/2048 @ Wo + bo) @ Wout + bout   (f32, tiny)
// ---------------------------------------------------------------------------
__global__ __launch_bounds__(256) void head_kernel(
    const float* __restrict__ pooled, const float* __restrict__ Wo,
    const float* __restrict__ bo, const float* __restrict__ Wout,
    const float* __restrict__ bout, float* __restrict__ out)
{
    int bq = blockIdx.x, tid = threadIdx.x;
    __shared__ float pl[128], mid[128];
    if (tid < 128) pl[tid] = pooled[bq * 128 + tid] * (1.f / 2048.f);
    __syncthreads();
    if (tid < 128) {
        float s = bo[tid];
#pragma unroll 4
        for (int c = 0; c < 128; ++c) s += pl[c] * Wo[c * 128 + tid];
        mid[tid] = s;
    }
    __syncthreads();
    for (int j = tid; j < 512; j += 256) {
        float s = bout[j];
#pragma unroll 4
        for (int i = 0; i < 128; ++i) s += mid[i] * Wout[i * 512 + j];
        out[bq * 512 + j] = s;
    }
}

// ---------------------------------------------------------------------------
extern "C" void kernel_launch(void* const* d_in, const int* in_sizes, int n_in,
                              void* d_out, int out_size, void* d_ws, size_t ws_size,
                              hipStream_t stream) {
    (void)in_sizes; (void)n_in; (void)out_size; (void)ws_size;
    const float* ohlc = (const float*)d_in[0];
    const float* Wp   = (const float*)d_in[1];  const float* bp   = (const float*)d_in[2];
    const float* Wc1  = (const float*)d_in[3];  const float* bc1  = (const float*)d_in[4];
    const float* Wc2  = (const float*)d_in[5];  const float* bc2  = (const float*)d_in[6];
    const float* Wv1  = (const float*)d_in[7];  const float* bv1  = (const float*)d_in[8];
    const float* Wv2  = (const float*)d_in[9];  const float* bv2  = (const float*)d_in[10];
    const float* Ws1  = (const float*)d_in[11]; const float* bs1  = (const float*)d_in[12];
    const float* Ws2  = (const float*)d_in[13]; const float* bs2  = (const float*)d_in[14];
    const float* Wqkv = (const float*)d_in[15]; const float* bqkv = (const float*)d_in[16];
    const float* Wo   = (const float*)d_in[17]; const float* bo   = (const float*)d_in[18];
    const float* Wout = (const float*)d_in[19]; const float* bout = (const float*)d_in[20];
    float* out = (float*)d_out;
    char* ws = (char*)d_ws;

    const size_t MB8 = 8388608;
    unsigned short* feats = (unsigned short*)(ws);
    unsigned short* qg    = (unsigned short*)(ws + 1 * MB8);
    unsigned short* kg    = (unsigned short*)(ws + 2 * MB8);
    unsigned short* vTg   = (unsigned short*)(ws + 3 * MB8);
    float*          pooled = (float*)(ws + 4 * MB8);
    float*          qkmax  = (float*)(ws + 4 * MB8 + 8192);
    unsigned short* wc1t  = (unsigned short*)(ws + 4 * MB8 + 8192 + 512);
    unsigned short* wc2t  = wc1t + 8192;
    unsigned short* wv1t  = wc2t + 4096;
    unsigned short* wv2t  = wv1t + 4096;
    unsigned short* ws1t  = wv2t + 1024;
    unsigned short* ws2t  = ws1t + 4096;
    unsigned short* wqkvt = ws2t + 1024;

    prep_kernel<<<97, 256, 0, stream>>>(Wc1, Wc2, Wv1, Wv2, Ws1, Ws2,
                                        wc1t, wc2t, wv1t, wv2t, ws1t, ws2t,
                                        pooled, qkmax);
    wqkv_trans<<<48, 256, 0, stream>>>(Wqkv, wqkvt);
    fused_mlp<<<512, 256, 0, stream>>>(ohlc, Wp, bp, wc1t, bc1, wc2t, bc2,
                                       wv1t, bv1, wv2t, bv2, ws1t, bs1, ws2t, bs2, feats);
    qkv_gemm<<<dim3(256, 3), 256, 0, stream>>>(feats, wqkvt, bqkv, qg, kg, vTg, qkmax);
    attn_kernel<<<1024, 256, 0, stream>>>(qg, kg, vTg, qkmax, pooled);
    head_kernel<<<16, 256, 0, stream>>>(pooled, Wo, bo, Wout, bout, out);
}